// Round 17
// baseline (359.758 us; speedup 1.0000x reference)
//
#include <hip/hip_runtime.h>

#define NN 50000
#define NE 400000
#define NBLK 196   // ceil(NN/256)

using short8 = __attribute__((ext_vector_type(8))) short;
using f32x4  = __attribute__((ext_vector_type(4))) float;
using f32x2  = __attribute__((ext_vector_type(2))) float;
using u16x2  = __attribute__((ext_vector_type(2))) unsigned short;
using u16x4  = __attribute__((ext_vector_type(4))) unsigned short;

__device__ __forceinline__ unsigned short f2b(float f) {
    union { float f; unsigned int u; } x; x.f = f;
    unsigned int u = x.u;
    u += 0x7fffu + ((u >> 16) & 1u);   // RNE
    return (unsigned short)(u >> 16);
}
__device__ __forceinline__ float b2f(unsigned short u) {
    union { unsigned int u; float f; } x; x.u = ((unsigned int)u) << 16;
    return x.f;
}

#define SWZ(b, row) ((b) ^ (((row) & 7) << 4))

// ---------------- CSR build ----------------
__global__ __launch_bounds__(256) void count_k(const int* __restrict__ dst, int* __restrict__ indeg) {
    int e = blockIdx.x * 256 + threadIdx.x;
    if (e < NE) atomicAdd(&indeg[dst[e]], 1);
}
__global__ __launch_bounds__(256) void scan1_k(const int* __restrict__ indeg, int* __restrict__ tmp,
                                               int* __restrict__ bsum) {
    __shared__ int s[256];
    int t = threadIdx.x, i = blockIdx.x * 256 + t;
    int v = (i < NN) ? indeg[i] : 0;
    s[t] = v; __syncthreads();
    for (int off = 1; off < 256; off <<= 1) {
        int x = (t >= off) ? s[t - off] : 0;
        __syncthreads();
        s[t] += x;
        __syncthreads();
    }
    if (i < NN) tmp[i] = s[t];
    if (t == 255) bsum[blockIdx.x] = s[255];
}
__global__ __launch_bounds__(256) void scan2_k(const int* __restrict__ bsum, int* __restrict__ boff) {
    __shared__ int s[256];
    int t = threadIdx.x;
    int v = (t < NBLK) ? bsum[t] : 0;
    s[t] = v; __syncthreads();
    for (int off = 1; off < 256; off <<= 1) {
        int x = (t >= off) ? s[t - off] : 0;
        __syncthreads();
        s[t] += x;
        __syncthreads();
    }
    if (t < NBLK) boff[t] = s[t] - v;   // exclusive
}
__global__ __launch_bounds__(256) void scan3_k(const int* __restrict__ tmp, const int* __restrict__ indeg,
                                               const int* __restrict__ boff, int* __restrict__ rowptr,
                                               float* __restrict__ dinv) {
    int i = blockIdx.x * 256 + threadIdx.x;
    if (i < NN) {
        rowptr[i] = tmp[i] - indeg[i] + boff[i >> 8];
        dinv[i] = rsqrtf((float)(1 + indeg[i]));
    }
    if (i == 0) rowptr[NN] = NE;
}
__global__ __launch_bounds__(256) void fill_k(const int* __restrict__ src, const int* __restrict__ dst,
                                              const float* __restrict__ dinv, const int* __restrict__ rowptr,
                                              int* __restrict__ cursor, int2* __restrict__ ebn) {
    int e = blockIdx.x * 256 + threadIdx.x;
    if (e >= NE) return;
    int s = src[e], d = dst[e];
    int pos = atomicAdd(&cursor[d], 1);
    ebn[rowptr[d] + pos] = make_int2(s, __float_as_int(dinv[s] * dinv[d]));
}

// ---------------- merged weight cast+transpose + zero (indeg,cursor) ----------------
struct WSegs {
    const float* W[9];
    unsigned short* Wt[9];
    int K[9], N[9], Kp[9];
    int c0[10];
    int* z1; int* z2;
};
__global__ __launch_bounds__(256) void wcast_zero_k(WSegs s) {
    int blk = blockIdx.x;
    if (blk >= s.c0[9]) {
        int i = (blk - s.c0[9]) * 256 + threadIdx.x;
        if (i < NN) { s.z1[i] = 0; s.z2[i] = 0; }
        return;
    }
    #pragma unroll
    for (int g = 0; g < 9; g++) {
        if (blk >= s.c0[g] && blk < s.c0[g + 1]) {
            int idx = (blk - s.c0[g]) * 256 + threadIdx.x;
            int Kp = s.Kp[g];
            int n = idx / Kp, k = idx % Kp;
            float v = (n < s.N[g] && k < s.K[g]) ? s.W[g][(size_t)k * s.N[g] + n] : 0.0f;
            s.Wt[g][idx] = f2b(v);
        }
    }
}

// ---------------- generic MFMA GEMM body: single-buffer LDS, reg prefetch ----------------
// C[M x ldc](bf16) = A[M x lda] @ Bt[BN x Kp]^T (+bias). NT threads, 2 row-groups of BM/2.
template<bool AF32, int BM, int BN, int NT>
__device__ __forceinline__ void gemm_body(
    const void* __restrict__ Araw, int lda, int Kp,
    const unsigned short* __restrict__ Bt, const float* __restrict__ bias,
    unsigned short* __restrict__ C, int N, int ldc, int M, int r0, char* lds) {
    constexpr int NW = NT / 64;
    constexpr int WC = NW / 2;            // col wave-groups
    constexpr int WBN = BN / WC;          // cols per wave
    constexpr int NF = WBN / 16;
    constexpr int MR = BM / 32;           // row frags per wave (row group = BM/2)
    constexpr int nA = (BM * 8) / NT;
    constexpr int nB = (BN * 8) / NT;

    int tid = threadIdx.x;
    int lane = tid & 63, wave = tid >> 6;
    int wr = wave / WC, wc = wave % WC;
    int lr = lane & 15, lk = lane >> 4;

    f32x4 acc[MR][NF];
    #pragma unroll
    for (int m = 0; m < MR; m++)
        #pragma unroll
        for (int n = 0; n < NF; n++)
            acc[m][n] = (f32x4){0.f, 0.f, 0.f, 0.f};

    float4 fa0[nA], fa1[nA];
    short8 ra[nA], rb[nB];

    auto LOAD = [&](int k0) {
        #pragma unroll
        for (int c = 0; c < nA; c++) {
            int o = tid + c * NT, row = o >> 3, oct = o & 7;
            int gr = min(r0 + row, M - 1);
            if constexpr (AF32) {
                const float* p = (const float*)Araw + (size_t)gr * lda + k0 + oct * 8;
                fa0[c] = *(const float4*)p;
                fa1[c] = *(const float4*)(p + 4);
            } else {
                ra[c] = *(const short8*)((const unsigned short*)Araw + (size_t)gr * lda + k0 + oct * 8);
            }
        }
        #pragma unroll
        for (int c = 0; c < nB; c++) {
            int o = tid + c * NT, row = o >> 3, oct = o & 7;
            rb[c] = *(const short8*)(Bt + (size_t)row * Kp + k0 + oct * 8);
        }
    };
    auto STORE = [&]() {
        char* AsB = lds;
        char* BsB = lds + BM * 128;
        #pragma unroll
        for (int c = 0; c < nA; c++) {
            int o = tid + c * NT, row = o >> 3, oct = o & 7;
            short8 v;
            if constexpr (AF32) {
                v[0] = (short)f2b(fa0[c].x); v[1] = (short)f2b(fa0[c].y);
                v[2] = (short)f2b(fa0[c].z); v[3] = (short)f2b(fa0[c].w);
                v[4] = (short)f2b(fa1[c].x); v[5] = (short)f2b(fa1[c].y);
                v[6] = (short)f2b(fa1[c].z); v[7] = (short)f2b(fa1[c].w);
            } else {
                v = ra[c];
            }
            *(short8*)(AsB + SWZ(row * 128 + oct * 16, row)) = v;
        }
        #pragma unroll
        for (int c = 0; c < nB; c++) {
            int o = tid + c * NT, row = o >> 3, oct = o & 7;
            *(short8*)(BsB + SWZ(row * 128 + oct * 16, row)) = rb[c];
        }
    };

    int nt = Kp >> 6;
    LOAD(0);
    STORE();
    __syncthreads();
    for (int t = 0; t < nt; t++) {
        if (t + 1 < nt) LOAD((t + 1) << 6);   // global loads in flight during MFMA
        char* AsB = lds;
        char* BsB = lds + BM * 128;
        #pragma unroll
        for (int kk = 0; kk < 2; kk++) {
            int kb = kk * 64 + lk * 16;
            short8 a[MR], b[NF];
            #pragma unroll
            for (int m = 0; m < MR; m++) {
                int row = wr * (BM / 2) + m * 16 + lr;
                a[m] = *(short8*)(AsB + SWZ(row * 128 + kb, row));
            }
            #pragma unroll
            for (int n = 0; n < NF; n++) {
                int row = wc * WBN + n * 16 + lr;
                b[n] = *(short8*)(BsB + SWZ(row * 128 + kb, row));
            }
            #pragma unroll
            for (int m = 0; m < MR; m++)
                #pragma unroll
                for (int n = 0; n < NF; n++)
                    acc[m][n] = __builtin_amdgcn_mfma_f32_16x16x32_bf16(a[m], b[n], acc[m][n], 0, 0, 0);
        }
        __syncthreads();
        if (t + 1 < nt) { STORE(); __syncthreads(); }
    }

    // epilogue: acc -> LDS (padded) -> coalesced short8 global writes
    constexpr int LDC = BN + 8;
    unsigned short* ldsC = (unsigned short*)lds;
    #pragma unroll
    for (int n = 0; n < NF; n++) {
        int gc = wc * WBN + n * 16 + lr;
        float bv = (bias != nullptr && gc < N) ? bias[gc] : 0.0f;
        bool ok = gc < N;
        #pragma unroll
        for (int m = 0; m < MR; m++)
            #pragma unroll
            for (int j = 0; j < 4; j++) {
                int row = wr * (BM / 2) + m * 16 + lk * 4 + j;
                float v = ok ? acc[m][n][j] + bv : 0.0f;
                ldsC[row * LDC + gc] = f2b(v);
            }
    }
    __syncthreads();
    constexpr int CH = (BM * BN / 8) / NT;
    #pragma unroll
    for (int c = 0; c < CH; c++) {
        int o = tid + c * NT;
        int row = o / (BN / 8), col = (o % (BN / 8)) * 8;
        int gr = r0 + row;
        if (gr < M)
            *(short8*)(C + (size_t)gr * ldc + col) = *(short8*)(ldsC + row * LDC + col);
    }
}

// LDS size: K-loop buffer vs epilogue C-tile, whichever larger
template<int BM, int BN>
constexpr int ldsz() {
    int a = (BM + BN) * 128;          // A+B tiles (bf16, swizzled)
    int b = BM * (BN + 8) * 2;        // padded C tile
    return a > b ? a : b;
}

// ---------------- fused L1: C1 = x@W1+b1 ; C2 = C1@Wg1  (BM=64, grid 782) --------------
__global__ __launch_bounds__(512) void fused_wide_k(
    const float* __restrict__ x, const unsigned short* __restrict__ W1t, const float* __restrict__ b1,
    unsigned short* __restrict__ C1, const unsigned short* __restrict__ Wg1t,
    unsigned short* __restrict__ C2, int M) {
    __shared__ __align__(16) char lds[ldsz<64, 256>()];   // 40 KB -> 4 blocks/CU
    int r0 = blockIdx.x * 64;
    gemm_body<true, 64, 256, 512>(x, 512, 512, W1t, b1, C1, 256, 256, M, r0, lds);
    __syncthreads();
    gemm_body<false, 64, 256, 512>(C1, 256, 256, Wg1t, nullptr, C2, 256, 256, M, r0, lds);
}

// ---------------- fused pair: C1 = A@W+b ; C2 = C1@Wg  (BM=128) ----------------
template<int BN>
__global__ __launch_bounds__(256) void fused_pair_k(
    const unsigned short* __restrict__ A1, int lda1, int Kp1,
    const unsigned short* __restrict__ B1t, const float* __restrict__ b1,
    unsigned short* __restrict__ C1, int N,
    const unsigned short* __restrict__ B2t, unsigned short* __restrict__ C2, int M) {
    __shared__ __align__(16) char lds[ldsz<128, BN>()];
    int r0 = blockIdx.x * 128;
    gemm_body<false, 128, BN, 256>(A1, lda1, Kp1, B1t, b1, C1, N, BN, M, r0, lds);
    __syncthreads();
    gemm_body<false, 128, BN, 256>(C1, BN, BN, B2t, nullptr, C2, N, BN, M, r0, lds);
}

// ---------------- single GEMM (L4-L6): C = A@Wg, 128x128 ----------------
__global__ __launch_bounds__(256) void gemm128_k(
    const unsigned short* __restrict__ A, const unsigned short* __restrict__ Bt,
    unsigned short* __restrict__ C, int M) {
    __shared__ __align__(16) char lds[ldsz<128, 128>()];   // 34 KB -> 4 blocks/CU
    gemm_body<false, 128, 128, 256>(A, 128, 128, Bt, nullptr, C, 128, 128, M, blockIdx.x * 128, lds);
}

// ---------------- fused GCN aggregate + combine (CSR gather, bf16) ----------------
template<int VEC> struct BV;
template<> struct BV<1> { using T = unsigned short; };
template<> struct BV<2> { using T = u16x2; };
template<> struct BV<4> { using T = u16x4; };
template<int VEC> struct FV;
template<> struct FV<1> { using T = float; };
template<> struct FV<2> { using T = f32x2; };
template<> struct FV<4> { using T = f32x4; };

template<int VEC, int SPLIT, bool OUTF32>
__global__ __launch_bounds__(256) void gather_k(
    const unsigned short* __restrict__ h, const unsigned short* __restrict__ base,
    const float* __restrict__ dinv, const float* __restrict__ bias,
    const int2* __restrict__ ebn, const int* __restrict__ rowptr,
    void* __restrict__ outraw, float alpha, int dorelu, int F) {
    constexpr int ld = 64 * VEC * SPLIT;
    int gw = (blockIdx.x * 256 + threadIdx.x) >> 6;
    int lane = threadIdx.x & 63;
    int w = gw / SPLIT;
    int colbase = (gw % SPLIT) * 64 * VEC;
    if (w >= NN) return;
    using LT = typename BV<VEC>::T;
    const int col = colbase + lane * VEC;

    float acc[VEC];
    float dn = dinv[w];
    {
        LT t = *(const LT*)(h + (size_t)w * ld + col);
        const unsigned short* tu = (const unsigned short*)&t;
        #pragma unroll
        for (int v = 0; v < VEC; v++) acc[v] = b2f(tu[v]) * dn * dn;
    }
    int e = rowptr[w], end = rowptr[w + 1];
    for (; e + 8 <= end; e += 8) {
        long long q[8];
        #pragma unroll
        for (int i = 0; i < 8; i++)
            q[i] = __builtin_nontemporal_load((const long long*)(ebn + e + i));
        LT t[8];
        #pragma unroll
        for (int i = 0; i < 8; i++)
            t[i] = *(const LT*)(h + (size_t)(int)q[i] * ld + col);
        #pragma unroll
        for (int i = 0; i < 8; i++) {
            float nr = __int_as_float((int)(q[i] >> 32));
            const unsigned short* u = (const unsigned short*)&t[i];
            #pragma unroll
            for (int v = 0; v < VEC; v++) acc[v] += b2f(u[v]) * nr;
        }
    }
    for (; e + 2 <= end; e += 2) {
        long long q0 = __builtin_nontemporal_load((const long long*)(ebn + e));
        long long q1 = __builtin_nontemporal_load((const long long*)(ebn + e + 1));
        LT t0 = *(const LT*)(h + (size_t)(int)q0 * ld + col);
        LT t1 = *(const LT*)(h + (size_t)(int)q1 * ld + col);
        float n0 = __int_as_float((int)(q0 >> 32)), n1 = __int_as_float((int)(q1 >> 32));
        const unsigned short* u0 = (const unsigned short*)&t0;
        const unsigned short* u1 = (const unsigned short*)&t1;
        #pragma unroll
        for (int v = 0; v < VEC; v++) acc[v] += b2f(u0[v]) * n0 + b2f(u1[v]) * n1;
    }
    if (e < end) {
        long long q0 = __builtin_nontemporal_load((const long long*)(ebn + e));
        LT t0 = *(const LT*)(h + (size_t)(int)q0 * ld + col);
        float n0 = __int_as_float((int)(q0 >> 32));
        const unsigned short* u0 = (const unsigned short*)&t0;
        #pragma unroll
        for (int v = 0; v < VEC; v++) acc[v] += b2f(u0[v]) * n0;
    }
    LT bt = *(const LT*)(base + (size_t)w * ld + col);
    const unsigned short* bu = (const unsigned short*)&bt;
    if (OUTF32) {
        typename FV<VEC>::T ot;
        float* of = (float*)&ot;
        #pragma unroll
        for (int v = 0; v < VEC; v++) {
            int f = col + v;
            float a = acc[v] + ((f < F) ? bias[f] : 0.0f);
            if (dorelu) a = fmaxf(a, 0.0f);
            of[v] = (f < F) ? b2f(bu[v]) + alpha * a : 0.0f;
        }
        *(typename FV<VEC>::T*)((float*)outraw + (size_t)w * ld + col) = ot;
    } else {
        LT ot;
        unsigned short* ou = (unsigned short*)&ot;
        #pragma unroll
        for (int v = 0; v < VEC; v++) {
            int f = col + v;
            float a = acc[v] + ((f < F) ? bias[f] : 0.0f);
            if (dorelu) a = fmaxf(a, 0.0f);
            float res = (f < F) ? b2f(bu[v]) + alpha * a : 0.0f;
            ou[v] = f2b(res);
        }
        *(LT*)((unsigned short*)outraw + (size_t)w * ld + col) = ot;
    }
}

extern "C" void kernel_launch(void* const* d_in, const int* in_sizes, int n_in,
                              void* d_out, int out_size, void* d_ws, size_t ws_size,
                              hipStream_t stream) {
    const float* x   = (const float*)d_in[0];
    const int*   ei  = (const int*)d_in[1];
    const float* W1  = (const float*)d_in[2];  const float* b1  = (const float*)d_in[3];
    const float* W2  = (const float*)d_in[4];  const float* b2  = (const float*)d_in[5];
    const float* W3  = (const float*)d_in[6];  const float* b3  = (const float*)d_in[7];
    const float* Wg1 = (const float*)d_in[8];  const float* bg1 = (const float*)d_in[9];
    const float* Wg2 = (const float*)d_in[10]; const float* bg2 = (const float*)d_in[11];
    const float* Wg3 = (const float*)d_in[12]; const float* bg3 = (const float*)d_in[13];
    const float* Wg4 = (const float*)d_in[14]; const float* bg4 = (const float*)d_in[15];
    const float* Wg5 = (const float*)d_in[16]; const float* bg5 = (const float*)d_in[17];
    const float* Wg6 = (const float*)d_in[18]; const float* bg6 = (const float*)d_in[19];
    const int* srcv = ei;
    const int* dstv = ei + NE;

    float* dinv = (float*)d_ws;
    unsigned short* hA = (unsigned short*)(dinv + 51200);   // NN x 256 bf16
    unsigned short* hB = hA + (size_t)NN * 256;
    unsigned short* hC = hB + (size_t)NN * 256;
    unsigned short* W1t  = hC + (size_t)NN * 256;
    unsigned short* Wg1t = W1t  + 256 * 512;
    unsigned short* W2t  = Wg1t + 256 * 256;
    unsigned short* Wg2t = W2t  + 64 * 256;
    unsigned short* W3t  = Wg2t + 64 * 64;
    unsigned short* Wg3t = W3t  + 128 * 64;
    unsigned short* Wg4t = Wg3t + 128 * 128;
    unsigned short* Wg5t = Wg4t + 128 * 128;
    unsigned short* Wg6t = Wg5t + 128 * 128;
    int* indeg  = (int*)(Wg6t + 128 * 128);
    int* cursor = indeg + 51200;
    int* tmp    = cursor + 51200;
    int* rowptr = tmp + 51200;
    int* bsum   = rowptr + 51264;
    int* boff   = bsum + 256;
    int2* ebn   = (int2*)(boff + 256);

    // weights cast+transpose AND zero(indeg,cursor) in one launch
    {
        WSegs s;
        const float* Ws[9] = {W1, Wg1, W2, Wg2, W3, Wg3, Wg4, Wg5, Wg6};
        unsigned short* Wts[9] = {W1t, Wg1t, W2t, Wg2t, W3t, Wg3t, Wg4t, Wg5t, Wg6t};
        int Ks[9]  = {512, 256, 256, 62, 62, 128, 128, 128, 128};
        int Ns[9]  = {256, 256, 62, 62, 128, 128, 128, 128, 128};
        int Kps[9] = {512, 256, 256, 64, 64, 128, 128, 128, 128};
        int Nps[9] = {256, 256, 64, 64, 128, 128, 128, 128, 128};
        int c = 0;
        for (int g = 0; g < 9; g++) {
            s.W[g] = Ws[g]; s.Wt[g] = Wts[g];
            s.K[g] = Ks[g]; s.N[g] = Ns[g]; s.Kp[g] = Kps[g];
            s.c0[g] = c;
            c += (Kps[g] * Nps[g]) / 256;
        }
        s.c0[9] = c;
        s.z1 = indeg; s.z2 = cursor;
        wcast_zero_k<<<c + NBLK, 256, 0, stream>>>(s);
    }
    count_k<<<(NE + 255) / 256, 256, 0, stream>>>(dstv, indeg);
    scan1_k<<<NBLK, 256, 0, stream>>>(indeg, tmp, bsum);
    scan2_k<<<1, 256, 0, stream>>>(bsum, boff);
    scan3_k<<<NBLK, 256, 0, stream>>>(tmp, indeg, boff, rowptr, dinv);
    fill_k<<<(NE + 255) / 256, 256, 0, stream>>>(srcv, dstv, dinv, rowptr, cursor, ebn);

    const int GX1 = (NN + 63) / 64;             // 782 (BM=64)
    const int GX2 = (NN + 127) / 128;           // 391 (BM=128)
    const int GG1 = (NN * 64 + 255) / 256;      // 1 wave/node

    // L1: x1l -> hA ; h -> hB (fused) ; x1 -> hC
    fused_wide_k<<<GX1, 512, 0, stream>>>(x, W1t, b1, hA, Wg1t, hB, NN);
    gather_k<4, 1, false><<<GG1, 256, 0, stream>>>(hB, hA, dinv, bg1, ebn, rowptr, hC, 1.0f, 1, 256);
    // L2: x2l -> hA ; h -> hB (fused) ; x2 -> hC   (ld 64)
    fused_pair_k<64><<<GX2, 256, 0, stream>>>(hC, 256, 256, W2t, b2, hA, 62, Wg2t, hB, NN);
    gather_k<1, 1, false><<<GG1, 256, 0, stream>>>(hB, hA, dinv, bg2, ebn, rowptr, hC, 1.0f, 1, 62);
    // L3: x3l -> hA ; h -> hB (fused) ; x3 -> hC   (ld 128)
    fused_pair_k<128><<<GX2, 256, 0, stream>>>(hC, 64, 64, W3t, b3, hA, 128, Wg3t, hB, NN);
    gather_k<2, 1, false><<<GG1, 256, 0, stream>>>(hB, hA, dinv, bg3, ebn, rowptr, hC, 0.5f, 1, 128);
    // L4: h -> hA ; x4 -> hB
    gemm128_k<<<GX2, 256, 0, stream>>>(hC, Wg4t, hA, NN);
    gather_k<2, 1, false><<<GG1, 256, 0, stream>>>(hA, hC, dinv, bg4, ebn, rowptr, hB, 0.5f, 1, 128);
    // L5: h -> hA ; x5 -> hC
    gemm128_k<<<GX2, 256, 0, stream>>>(hB, Wg5t, hA, NN);
    gather_k<2, 1, false><<<GG1, 256, 0, stream>>>(hA, hB, dinv, bg5, ebn, rowptr, hC, 0.25f, 1, 128);
    // L6: h -> hA ; x6 -> d_out (fp32)
    gemm128_k<<<GX2, 256, 0, stream>>>(hC, Wg6t, hA, NN);
    gather_k<2, 1, true><<<GG1, 256, 0, stream>>>(hA, hC, dinv, bg6, ebn, rowptr, d_out, 0.25f, 0, 128);
}

// Round 19
// 355.471 us; speedup vs baseline: 1.0121x; 1.0121x over previous
//
#include <hip/hip_runtime.h>

#define NN 50000
#define NE 400000
#define NBLK 196   // ceil(NN/256)

using short8 = __attribute__((ext_vector_type(8))) short;
using f32x4  = __attribute__((ext_vector_type(4))) float;
using f32x2  = __attribute__((ext_vector_type(2))) float;
using u16x2  = __attribute__((ext_vector_type(2))) unsigned short;
using u16x4  = __attribute__((ext_vector_type(4))) unsigned short;

__device__ __forceinline__ unsigned short f2b(float f) {
    union { float f; unsigned int u; } x; x.f = f;
    unsigned int u = x.u;
    u += 0x7fffu + ((u >> 16) & 1u);   // RNE
    return (unsigned short)(u >> 16);
}
__device__ __forceinline__ float b2f(unsigned short u) {
    union { unsigned int u; float f; } x; x.u = ((unsigned int)u) << 16;
    return x.f;
}

#define SWZ(b, row) ((b) ^ (((row) & 7) << 4))

// ---------------- CSR build ----------------
__global__ __launch_bounds__(256) void count_k(const int* __restrict__ dst, int* __restrict__ indeg) {
    int e = blockIdx.x * 256 + threadIdx.x;
    if (e < NE) atomicAdd(&indeg[dst[e]], 1);
}
__global__ __launch_bounds__(256) void scan1_k(const int* __restrict__ indeg, int* __restrict__ tmp,
                                               int* __restrict__ bsum) {
    __shared__ int s[256];
    int t = threadIdx.x, i = blockIdx.x * 256 + t;
    int v = (i < NN) ? indeg[i] : 0;
    s[t] = v; __syncthreads();
    for (int off = 1; off < 256; off <<= 1) {
        int x = (t >= off) ? s[t - off] : 0;
        __syncthreads();
        s[t] += x;
        __syncthreads();
    }
    if (i < NN) tmp[i] = s[t];
    if (t == 255) bsum[blockIdx.x] = s[255];
}
__global__ __launch_bounds__(256) void scan2_k(const int* __restrict__ bsum, int* __restrict__ boff) {
    __shared__ int s[256];
    int t = threadIdx.x;
    int v = (t < NBLK) ? bsum[t] : 0;
    s[t] = v; __syncthreads();
    for (int off = 1; off < 256; off <<= 1) {
        int x = (t >= off) ? s[t - off] : 0;
        __syncthreads();
        s[t] += x;
        __syncthreads();
    }
    if (t < NBLK) boff[t] = s[t] - v;   // exclusive
}
__global__ __launch_bounds__(256) void scan3_k(const int* __restrict__ tmp, const int* __restrict__ indeg,
                                               const int* __restrict__ boff, int* __restrict__ rowptr,
                                               float* __restrict__ dinv) {
    int i = blockIdx.x * 256 + threadIdx.x;
    if (i < NN) {
        rowptr[i] = tmp[i] - indeg[i] + boff[i >> 8];
        dinv[i] = rsqrtf((float)(1 + indeg[i]));
    }
    if (i == 0) rowptr[NN] = NE;
}
__global__ __launch_bounds__(256) void fill_k(const int* __restrict__ src, const int* __restrict__ dst,
                                              const float* __restrict__ dinv, const int* __restrict__ rowptr,
                                              int* __restrict__ cursor, int2* __restrict__ ebn) {
    int e = blockIdx.x * 256 + threadIdx.x;
    if (e >= NE) return;
    int s = src[e], d = dst[e];
    int pos = atomicAdd(&cursor[d], 1);
    ebn[rowptr[d] + pos] = make_int2(s, __float_as_int(dinv[s] * dinv[d]));
}

// ---------------- merged weight cast+transpose + zero (indeg,cursor) ----------------
struct WSegs {
    const float* W[9];
    unsigned short* Wt[9];
    int K[9], N[9], Kp[9];
    int c0[10];
    int* z1; int* z2;
};
__global__ __launch_bounds__(256) void wcast_zero_k(WSegs s) {
    int blk = blockIdx.x;
    if (blk >= s.c0[9]) {
        int i = (blk - s.c0[9]) * 256 + threadIdx.x;
        if (i < NN) { s.z1[i] = 0; s.z2[i] = 0; }
        return;
    }
    #pragma unroll
    for (int g = 0; g < 9; g++) {
        if (blk >= s.c0[g] && blk < s.c0[g + 1]) {
            int idx = (blk - s.c0[g]) * 256 + threadIdx.x;
            int Kp = s.Kp[g];
            int n = idx / Kp, k = idx % Kp;
            float v = (n < s.N[g] && k < s.K[g]) ? s.W[g][(size_t)k * s.N[g] + n] : 0.0f;
            s.Wt[g][idx] = f2b(v);
        }
    }
}

// ================= GEMM stage 1: C = A @ Bt^T (+bias), epilogue -> aswz (A-format) + global
// aswz: BN/64 subtiles of [BM][64k] bf16, SWZ'd — directly consumable as stage-2 A tiles.
template<bool AF32, int BM, int BN, int NT>
__device__ __forceinline__ void gemm_stage1(
    const void* __restrict__ Araw, int lda, int Kp,
    const unsigned short* __restrict__ Bt, const float* __restrict__ bias,
    unsigned short* __restrict__ C, int N, int ldc, int M, int r0,
    char* lds, char* aswz) {
    constexpr int NW = NT / 64;
    constexpr int WC = NW / 2;
    constexpr int WBN = BN / WC;
    constexpr int NF = WBN / 16;
    constexpr int MR = BM / 32;
    constexpr int nA = (BM * 8) / NT;
    constexpr int nB = (BN * 8) / NT;

    int tid = threadIdx.x;
    int lane = tid & 63, wave = tid >> 6;
    int wr = wave / WC, wc = wave % WC;
    int lr = lane & 15, lk = lane >> 4;

    f32x4 acc[MR][NF];
    #pragma unroll
    for (int m = 0; m < MR; m++)
        #pragma unroll
        for (int n = 0; n < NF; n++)
            acc[m][n] = (f32x4){0.f, 0.f, 0.f, 0.f};

    float4 fa0[nA], fa1[nA];
    short8 ra[nA], rb[nB];

    auto LOAD = [&](int k0) {
        #pragma unroll
        for (int c = 0; c < nA; c++) {
            int o = tid + c * NT, row = o >> 3, oct = o & 7;
            int gr = min(r0 + row, M - 1);
            if constexpr (AF32) {
                const float* p = (const float*)Araw + (size_t)gr * lda + k0 + oct * 8;
                fa0[c] = *(const float4*)p;
                fa1[c] = *(const float4*)(p + 4);
            } else {
                ra[c] = *(const short8*)((const unsigned short*)Araw + (size_t)gr * lda + k0 + oct * 8);
            }
        }
        #pragma unroll
        for (int c = 0; c < nB; c++) {
            int o = tid + c * NT, row = o >> 3, oct = o & 7;
            rb[c] = *(const short8*)(Bt + (size_t)row * Kp + k0 + oct * 8);
        }
    };
    auto STORE = [&]() {
        char* AsB = lds;
        char* BsB = lds + BM * 128;
        #pragma unroll
        for (int c = 0; c < nA; c++) {
            int o = tid + c * NT, row = o >> 3, oct = o & 7;
            short8 v;
            if constexpr (AF32) {
                v[0] = (short)f2b(fa0[c].x); v[1] = (short)f2b(fa0[c].y);
                v[2] = (short)f2b(fa0[c].z); v[3] = (short)f2b(fa0[c].w);
                v[4] = (short)f2b(fa1[c].x); v[5] = (short)f2b(fa1[c].y);
                v[6] = (short)f2b(fa1[c].z); v[7] = (short)f2b(fa1[c].w);
            } else {
                v = ra[c];
            }
            *(short8*)(AsB + SWZ(row * 128 + oct * 16, row)) = v;
        }
        #pragma unroll
        for (int c = 0; c < nB; c++) {
            int o = tid + c * NT, row = o >> 3, oct = o & 7;
            *(short8*)(BsB + SWZ(row * 128 + oct * 16, row)) = rb[c];
        }
    };

    int nt = Kp >> 6;
    LOAD(0);
    STORE();
    __syncthreads();
    for (int t = 0; t < nt; t++) {
        if (t + 1 < nt) LOAD((t + 1) << 6);
        char* AsB = lds;
        char* BsB = lds + BM * 128;
        #pragma unroll
        for (int kk = 0; kk < 2; kk++) {
            int kb = kk * 64 + lk * 16;
            short8 a[MR], b[NF];
            #pragma unroll
            for (int m = 0; m < MR; m++) {
                int row = wr * (BM / 2) + m * 16 + lr;
                a[m] = *(short8*)(AsB + SWZ(row * 128 + kb, row));
            }
            #pragma unroll
            for (int n = 0; n < NF; n++) {
                int row = wc * WBN + n * 16 + lr;
                b[n] = *(short8*)(BsB + SWZ(row * 128 + kb, row));
            }
            #pragma unroll
            for (int m = 0; m < MR; m++)
                #pragma unroll
                for (int n = 0; n < NF; n++)
                    acc[m][n] = __builtin_amdgcn_mfma_f32_16x16x32_bf16(a[m], b[n], acc[m][n], 0, 0, 0);
        }
        __syncthreads();
        if (t + 1 < nt) { STORE(); __syncthreads(); }
    }

    // epilogue: acc -> aswz (A-format subtiles), then global from aswz
    #pragma unroll
    for (int n = 0; n < NF; n++) {
        int gc = wc * WBN + n * 16 + lr;
        float bv = (bias != nullptr && gc < N) ? bias[gc] : 0.0f;
        bool ok = gc < N;
        int sub = gc >> 6, kin = gc & 63;
        char* base = aswz + sub * (BM * 128) + (kin & 7) * 2;
        #pragma unroll
        for (int m = 0; m < MR; m++)
            #pragma unroll
            for (int j = 0; j < 4; j++) {
                int row = wr * (BM / 2) + m * 16 + lk * 4 + j;
                float v = ok ? acc[m][n][j] + bv : 0.0f;
                *(unsigned short*)(base + SWZ(row * 128 + (kin >> 3) * 16, row)) = f2b(v);
            }
    }
    __syncthreads();
    constexpr int CH = (BM * BN / 8) / NT;
    #pragma unroll
    for (int c = 0; c < CH; c++) {
        int o = tid + c * NT;
        int row = o / (BN / 8), cg = o % (BN / 8);
        int sub = cg >> 3, oct = cg & 7;
        short8 v = *(short8*)(aswz + sub * (BM * 128) + SWZ(row * 128 + oct * 16, row));
        int gr = r0 + row;
        if (gr < M)
            *(short8*)(C + (size_t)gr * ldc + sub * 64 + oct * 8) = v;
    }
}

// ================= GEMM stage 2: C2 = aswz(A) @ Bt2^T ; A resident in LDS ==============
template<int BM, int ON, int NT>
__device__ __forceinline__ void gemm_stage2(
    const char* __restrict__ aswz, const unsigned short* __restrict__ Bt, int Kp,
    unsigned short* __restrict__ C, int N, int ldc, int M, int r0,
    char* ldsB, unsigned short* ldsC) {
    constexpr int NW = NT / 64;
    constexpr int WC = NW / 2;
    constexpr int WBN = ON / WC;
    constexpr int NF = WBN / 16;
    constexpr int MR = BM / 32;
    constexpr int nB = (ON * 8) / NT;

    int tid = threadIdx.x;
    int lane = tid & 63, wave = tid >> 6;
    int wr = wave / WC, wc = wave % WC;
    int lr = lane & 15, lk = lane >> 4;

    f32x4 acc[MR][NF];
    #pragma unroll
    for (int m = 0; m < MR; m++)
        #pragma unroll
        for (int n = 0; n < NF; n++)
            acc[m][n] = (f32x4){0.f, 0.f, 0.f, 0.f};

    short8 rb[nB];
    auto LOADB = [&](int k0) {
        #pragma unroll
        for (int c = 0; c < nB; c++) {
            int o = tid + c * NT, row = o >> 3, oct = o & 7;
            rb[c] = *(const short8*)(Bt + (size_t)row * Kp + k0 + oct * 8);
        }
    };
    auto STOREB = [&]() {
        #pragma unroll
        for (int c = 0; c < nB; c++) {
            int o = tid + c * NT, row = o >> 3, oct = o & 7;
            *(short8*)(ldsB + SWZ(row * 128 + oct * 16, row)) = rb[c];
        }
    };

    int nt = Kp >> 6;
    LOADB(0);
    STOREB();
    __syncthreads();
    for (int t = 0; t < nt; t++) {
        if (t + 1 < nt) LOADB((t + 1) << 6);
        const char* AsB = aswz + t * (BM * 128);
        #pragma unroll
        for (int kk = 0; kk < 2; kk++) {
            int kb = kk * 64 + lk * 16;
            short8 a[MR], b[NF];
            #pragma unroll
            for (int m = 0; m < MR; m++) {
                int row = wr * (BM / 2) + m * 16 + lr;
                a[m] = *(short8*)(AsB + SWZ(row * 128 + kb, row));
            }
            #pragma unroll
            for (int n = 0; n < NF; n++) {
                int row = wc * WBN + n * 16 + lr;
                b[n] = *(short8*)(ldsB + SWZ(row * 128 + kb, row));
            }
            #pragma unroll
            for (int m = 0; m < MR; m++)
                #pragma unroll
                for (int n = 0; n < NF; n++)
                    acc[m][n] = __builtin_amdgcn_mfma_f32_16x16x32_bf16(a[m], b[n], acc[m][n], 0, 0, 0);
        }
        __syncthreads();
        if (t + 1 < nt) { STOREB(); __syncthreads(); }
    }

    // standard epilogue via padded ldsC
    constexpr int LDC = ON + 8;
    #pragma unroll
    for (int n = 0; n < NF; n++) {
        int gc = wc * WBN + n * 16 + lr;
        bool ok = gc < N;
        #pragma unroll
        for (int m = 0; m < MR; m++)
            #pragma unroll
            for (int j = 0; j < 4; j++) {
                int row = wr * (BM / 2) + m * 16 + lk * 4 + j;
                float v = ok ? acc[m][n][j] : 0.0f;
                ldsC[row * LDC + gc] = f2b(v);
            }
    }
    __syncthreads();
    constexpr int CH = (BM * ON / 8) / NT;
    #pragma unroll
    for (int c = 0; c < CH; c++) {
        int o = tid + c * NT;
        int row = o / (ON / 8), col = (o % (ON / 8)) * 8;
        int gr = r0 + row;
        if (gr < M)
            *(short8*)(C + (size_t)gr * ldc + col) = *(short8*)(ldsC + row * LDC + col);
    }
}

// ---------------- fused L1: BM=64, 512 thr. lds: loop 40K | aswz 32K @40960 ----------
__global__ __launch_bounds__(512) void fused_wide_k(
    const float* __restrict__ x, const unsigned short* __restrict__ W1t, const float* __restrict__ b1,
    unsigned short* __restrict__ C1, const unsigned short* __restrict__ Wg1t,
    unsigned short* __restrict__ C2, int M) {
    __shared__ __align__(16) char lds[73728];   // 72 KB -> 2 blocks/CU
    char* aswz = lds + 40960;
    int r0 = blockIdx.x * 64;
    gemm_stage1<true, 64, 256, 512>(x, 512, 512, W1t, b1, C1, 256, 256, M, r0, lds, aswz);
    __syncthreads();
    gemm_stage2<64, 256, 512>(aswz, Wg1t, 256, C2, 256, 256, M, r0, lds, (unsigned short*)lds);
}

// ---------------- fused pair: BM=128 ----------------
template<int BN>
__global__ __launch_bounds__(256) void fused_pair_k(
    const unsigned short* __restrict__ A1, int lda1, int Kp1,
    const unsigned short* __restrict__ B1t, const float* __restrict__ b1,
    unsigned short* __restrict__ C1, int N,
    const unsigned short* __restrict__ B2t, unsigned short* __restrict__ C2, int M) {
    constexpr int LOOP1 = (128 + BN) * 128;
    constexpr int ASWZ  = 128 * BN * 2;
    constexpr int LDSC  = 128 * (BN + 8) * 2;
    constexpr int TOT   = LOOP1 + ASWZ > LDSC ? LOOP1 + ASWZ : LDSC;
    __shared__ __align__(16) char lds[TOT];
    char* aswz = lds + LOOP1;
    int r0 = blockIdx.x * 128;
    gemm_stage1<false, 128, BN, 256>(A1, lda1, Kp1, B1t, b1, C1, N, BN, M, r0, lds, aswz);
    __syncthreads();
    gemm_stage2<128, BN, 256>(aswz, B2t, BN, C2, N, BN, M, r0, lds, (unsigned short*)lds);
}

// ---------------- single GEMM (L4-L6): C = A@Wg, 128x128 (NF=4 FIXED) -------------
__global__ __launch_bounds__(256) void gemm128_k(
    const unsigned short* __restrict__ A, const unsigned short* __restrict__ Bt,
    unsigned short* __restrict__ C, int M) {
    constexpr int BM = 128, BN = 128, NT = 256;
    constexpr int TOT = 128 * (128 + 8) * 2;   // ldsC dominates (34816 > 32768)
    __shared__ __align__(16) char lds[TOT];
    constexpr int NF = 4, MR = 4;              // wave tile 64 rows x 64 cols
    int tid = threadIdx.x;
    int lane = tid & 63, wave = tid >> 6;
    int wr = wave >> 1, wc = wave & 1;
    int lr = lane & 15, lk = lane >> 4;
    int r0 = blockIdx.x * BM;

    f32x4 acc[MR][NF];
    #pragma unroll
    for (int m = 0; m < MR; m++)
        #pragma unroll
        for (int n = 0; n < NF; n++)
            acc[m][n] = (f32x4){0.f, 0.f, 0.f, 0.f};

    short8 ra[4], rb[4];
    auto LOAD = [&](int k0) {
        #pragma unroll
        for (int c = 0; c < 4; c++) {
            int o = tid + c * NT, row = o >> 3, oct = o & 7;
            int gr = min(r0 + row, M - 1);
            ra[c] = *(const short8*)(A + (size_t)gr * 128 + k0 + oct * 8);
        }
        #pragma unroll
        for (int c = 0; c < 4; c++) {
            int o = tid + c * NT, row = o >> 3, oct = o & 7;
            rb[c] = *(const short8*)(Bt + (size_t)row * 128 + k0 + oct * 8);
        }
    };
    auto STORE = [&]() {
        #pragma unroll
        for (int c = 0; c < 4; c++) {
            int o = tid + c * NT, row = o >> 3, oct = o & 7;
            *(short8*)(lds + SWZ(row * 128 + oct * 16, row)) = ra[c];
        }
        #pragma unroll
        for (int c = 0; c < 4; c++) {
            int o = tid + c * NT, row = o >> 3, oct = o & 7;
            *(short8*)(lds + BM * 128 + SWZ(row * 128 + oct * 16, row)) = rb[c];
        }
    };

    LOAD(0);
    STORE();
    __syncthreads();
    for (int t = 0; t < 2; t++) {
        if (t == 0) LOAD(64);
        #pragma unroll
        for (int kk = 0; kk < 2; kk++) {
            int kb = kk * 64 + lk * 16;
            short8 a[MR], b[NF];
            #pragma unroll
            for (int m = 0; m < MR; m++) {
                int row = wr * 64 + m * 16 + lr;
                a[m] = *(short8*)(lds + SWZ(row * 128 + kb, row));
            }
            #pragma unroll
            for (int n = 0; n < NF; n++) {
                int row = wc * 64 + n * 16 + lr;
                b[n] = *(short8*)(lds + BM * 128 + SWZ(row * 128 + kb, row));
            }
            #pragma unroll
            for (int m = 0; m < MR; m++)
                #pragma unroll
                for (int n = 0; n < NF; n++)
                    acc[m][n] = __builtin_amdgcn_mfma_f32_16x16x32_bf16(a[m], b[n], acc[m][n], 0, 0, 0);
        }
        __syncthreads();
        if (t == 0) { STORE(); __syncthreads(); }
    }

    constexpr int LDC = BN + 8;
    unsigned short* ldsC = (unsigned short*)lds;
    #pragma unroll
    for (int n = 0; n < NF; n++) {
        int gc = wc * 64 + n * 16 + lr;
        #pragma unroll
        for (int m = 0; m < MR; m++)
            #pragma unroll
            for (int j = 0; j < 4; j++) {
                int row = wr * 64 + m * 16 + lk * 4 + j;
                ldsC[row * LDC + gc] = f2b(acc[m][n][j]);
            }
    }
    __syncthreads();
    #pragma unroll
    for (int c = 0; c < 8; c++) {
        int o = tid + c * NT;
        int row = o >> 4, col = (o & 15) * 8;
        int gr = r0 + row;
        if (gr < M)
            *(short8*)(C + (size_t)gr * 128 + col) = *(short8*)(ldsC + row * LDC + col);
    }
}

// ---------------- fused GCN aggregate + combine (CSR gather, bf16) ----------------
template<int VEC> struct BV;
template<> struct BV<1> { using T = unsigned short; };
template<> struct BV<2> { using T = u16x2; };
template<> struct BV<4> { using T = u16x4; };
template<int VEC> struct FV;
template<> struct FV<1> { using T = float; };
template<> struct FV<2> { using T = f32x2; };
template<> struct FV<4> { using T = f32x4; };

template<int VEC, int SPLIT, bool OUTF32>
__global__ __launch_bounds__(256) void gather_k(
    const unsigned short* __restrict__ h, const unsigned short* __restrict__ base,
    const float* __restrict__ dinv, const float* __restrict__ bias,
    const int2* __restrict__ ebn, const int* __restrict__ rowptr,
    void* __restrict__ outraw, float alpha, int dorelu, int F) {
    constexpr int ld = 64 * VEC * SPLIT;
    int gw = (blockIdx.x * 256 + threadIdx.x) >> 6;
    int lane = threadIdx.x & 63;
    int w = gw / SPLIT;
    int colbase = (gw % SPLIT) * 64 * VEC;
    if (w >= NN) return;
    using LT = typename BV<VEC>::T;
    const int col = colbase + lane * VEC;

    float acc[VEC];
    float dn = dinv[w];
    {
        LT t = *(const LT*)(h + (size_t)w * ld + col);
        const unsigned short* tu = (const unsigned short*)&t;
        #pragma unroll
        for (int v = 0; v < VEC; v++) acc[v] = b2f(tu[v]) * dn * dn;
    }
    int e = rowptr[w], end = rowptr[w + 1];
    for (; e + 8 <= end; e += 8) {
        long long q[8];
        #pragma unroll
        for (int i = 0; i < 8; i++)
            q[i] = __builtin_nontemporal_load((const long long*)(ebn + e + i));
        LT t[8];
        #pragma unroll
        for (int i = 0; i < 8; i++)
            t[i] = *(const LT*)(h + (size_t)(int)q[i] * ld + col);
        #pragma unroll
        for (int i = 0; i < 8; i++) {
            float nr = __int_as_float((int)(q[i] >> 32));
            const unsigned short* u = (const unsigned short*)&t[i];
            #pragma unroll
            for (int v = 0; v < VEC; v++) acc[v] += b2f(u[v]) * nr;
        }
    }
    for (; e + 2 <= end; e += 2) {
        long long q0 = __builtin_nontemporal_load((const long long*)(ebn + e));
        long long q1 = __builtin_nontemporal_load((const long long*)(ebn + e + 1));
        LT t0 = *(const LT*)(h + (size_t)(int)q0 * ld + col);
        LT t1 = *(const LT*)(h + (size_t)(int)q1 * ld + col);
        float n0 = __int_as_float((int)(q0 >> 32)), n1 = __int_as_float((int)(q1 >> 32));
        const unsigned short* u0 = (const unsigned short*)&t0;
        const unsigned short* u1 = (const unsigned short*)&t1;
        #pragma unroll
        for (int v = 0; v < VEC; v++) acc[v] += b2f(u0[v]) * n0 + b2f(u1[v]) * n1;
    }
    if (e < end) {
        long long q0 = __builtin_nontemporal_load((const long long*)(ebn + e));
        LT t0 = *(const LT*)(h + (size_t)(int)q0 * ld + col);
        float n0 = __int_as_float((int)(q0 >> 32));
        const unsigned short* u0 = (const unsigned short*)&t0;
        #pragma unroll
        for (int v = 0; v < VEC; v++) acc[v] += b2f(u0[v]) * n0;
    }
    LT bt = *(const LT*)(base + (size_t)w * ld + col);
    const unsigned short* bu = (const unsigned short*)&bt;
    if (OUTF32) {
        typename FV<VEC>::T ot;
        float* of = (float*)&ot;
        #pragma unroll
        for (int v = 0; v < VEC; v++) {
            int f = col + v;
            float a = acc[v] + ((f < F) ? bias[f] : 0.0f);
            if (dorelu) a = fmaxf(a, 0.0f);
            of[v] = (f < F) ? b2f(bu[v]) + alpha * a : 0.0f;
        }
        *(typename FV<VEC>::T*)((float*)outraw + (size_t)w * ld + col) = ot;
    } else {
        LT ot;
        unsigned short* ou = (unsigned short*)&ot;
        #pragma unroll
        for (int v = 0; v < VEC; v++) {
            int f = col + v;
            float a = acc[v] + ((f < F) ? bias[f] : 0.0f);
            if (dorelu) a = fmaxf(a, 0.0f);
            float res = (f < F) ? b2f(bu[v]) + alpha * a : 0.0f;
            ou[v] = f2b(res);
        }
        *(LT*)((unsigned short*)outraw + (size_t)w * ld + col) = ot;
    }
}

extern "C" void kernel_launch(void* const* d_in, const int* in_sizes, int n_in,
                              void* d_out, int out_size, void* d_ws, size_t ws_size,
                              hipStream_t stream) {
    const float* x   = (const float*)d_in[0];
    const int*   ei  = (const int*)d_in[1];
    const float* W1  = (const float*)d_in[2];  const float* b1  = (const float*)d_in[3];
    const float* W2  = (const float*)d_in[4];  const float* b2  = (const float*)d_in[5];
    const float* W3  = (const float*)d_in[6];  const float* b3  = (const float*)d_in[7];
    const float* Wg1 = (const float*)d_in[8];  const float* bg1 = (const float*)d_in[9];
    const float* Wg2 = (const float*)d_in[10]; const float* bg2 = (const float*)d_in[11];
    const float* Wg3 = (const float*)d_in[12]; const float* bg3 = (const float*)d_in[13];
    const float* Wg4 = (const float*)d_in[14]; const float* bg4 = (const float*)d_in[15];
    const float* Wg5 = (const float*)d_in[16]; const float* bg5 = (const float*)d_in[17];
    const float* Wg6 = (const float*)d_in[18]; const float* bg6 = (const float*)d_in[19];
    const int* srcv = ei;
    const int* dstv = ei + NE;

    float* dinv = (float*)d_ws;
    unsigned short* hA = (unsigned short*)(dinv + 51200);   // NN x 256 bf16
    unsigned short* hB = hA + (size_t)NN * 256;
    unsigned short* hC = hB + (size_t)NN * 256;
    unsigned short* W1t  = hC + (size_t)NN * 256;
    unsigned short* Wg1t = W1t  + 256 * 512;
    unsigned short* W2t  = Wg1t + 256 * 256;
    unsigned short* Wg2t = W2t  + 64 * 256;
    unsigned short* W3t  = Wg2t + 64 * 64;
    unsigned short* Wg3t = W3t  + 128 * 64;
    unsigned short* Wg4t = Wg3t + 128 * 128;
    unsigned short* Wg5t = Wg4t + 128 * 128;
    unsigned short* Wg6t = Wg5t + 128 * 128;
    int* indeg  = (int*)(Wg6t + 128 * 128);
    int* cursor = indeg + 51200;
    int* tmp    = cursor + 51200;
    int* rowptr = tmp + 51200;
    int* bsum   = rowptr + 51264;
    int* boff   = bsum + 256;
    int2* ebn   = (int2*)(boff + 256);

    // weights cast+transpose AND zero(indeg,cursor) in one launch
    {
        WSegs s;
        const float* Ws[9] = {W1, Wg1, W2, Wg2, W3, Wg3, Wg4, Wg5, Wg6};
        unsigned short* Wts[9] = {W1t, Wg1t, W2t, Wg2t, W3t, Wg3t, Wg4t, Wg5t, Wg6t};
        int Ks[9]  = {512, 256, 256, 62, 62, 128, 128, 128, 128};
        int Ns[9]  = {256, 256, 62, 62, 128, 128, 128, 128, 128};
        int Kps[9] = {512, 256, 256, 64, 64, 128, 128, 128, 128};
        int Nps[9] = {256, 256, 64, 64, 128, 128, 128, 128, 128};
        int c = 0;
        for (int g = 0; g < 9; g++) {
            s.W[g] = Ws[g]; s.Wt[g] = Wts[g];
            s.K[g] = Ks[g]; s.N[g] = Ns[g]; s.Kp[g] = Kps[g];
            s.c0[g] = c;
            c += (Kps[g] * Nps[g]) / 256;
        }
        s.c0[9] = c;
        s.z1 = indeg; s.z2 = cursor;
        wcast_zero_k<<<c + NBLK, 256, 0, stream>>>(s);
    }
    count_k<<<(NE + 255) / 256, 256, 0, stream>>>(dstv, indeg);
    scan1_k<<<NBLK, 256, 0, stream>>>(indeg, tmp, bsum);
    scan2_k<<<1, 256, 0, stream>>>(bsum, boff);
    scan3_k<<<NBLK, 256, 0, stream>>>(tmp, indeg, boff, rowptr, dinv);
    fill_k<<<(NE + 255) / 256, 256, 0, stream>>>(srcv, dstv, dinv, rowptr, cursor, ebn);

    const int GX1 = (NN + 63) / 64;             // 782 (BM=64)
    const int GX2 = (NN + 127) / 128;           // 391 (BM=128)
    const int GG1 = (NN * 64 + 255) / 256;      // 1 wave/node

    // L1: x1l -> hA ; h -> hB (fused, stage2 A in LDS) ; x1 -> hC
    fused_wide_k<<<GX1, 512, 0, stream>>>(x, W1t, b1, hA, Wg1t, hB, NN);
    gather_k<4, 1, false><<<GG1, 256, 0, stream>>>(hB, hA, dinv, bg1, ebn, rowptr, hC, 1.0f, 1, 256);
    // L2: x2l -> hA ; h -> hB (fused) ; x2 -> hC   (ld 64)
    fused_pair_k<64><<<GX2, 256, 0, stream>>>(hC, 256, 256, W2t, b2, hA, 62, Wg2t, hB, NN);
    gather_k<1, 1, false><<<GG1, 256, 0, stream>>>(hB, hA, dinv, bg2, ebn, rowptr, hC, 1.0f, 1, 62);
    // L3: x3l -> hA ; h -> hB (fused) ; x3 -> hC   (ld 128)
    fused_pair_k<128><<<GX2, 256, 0, stream>>>(hC, 64, 64, W3t, b3, hA, 128, Wg3t, hB, NN);
    gather_k<2, 1, false><<<GG1, 256, 0, stream>>>(hB, hA, dinv, bg3, ebn, rowptr, hC, 0.5f, 1, 128);
    // L4: h -> hA ; x4 -> hB
    gemm128_k<<<GX2, 256, 0, stream>>>(hC, Wg4t, hA, NN);
    gather_k<2, 1, false><<<GG1, 256, 0, stream>>>(hA, hC, dinv, bg4, ebn, rowptr, hB, 0.5f, 1, 128);
    // L5: h -> hA ; x5 -> hC
    gemm128_k<<<GX2, 256, 0, stream>>>(hB, Wg5t, hA, NN);
    gather_k<2, 1, false><<<GG1, 256, 0, stream>>>(hA, hB, dinv, bg5, ebn, rowptr, hC, 0.25f, 1, 128);
    // L6: h -> hA ; x6 -> d_out (fp32)
    gemm128_k<<<GX2, 256, 0, stream>>>(hC, Wg6t, hA, NN);
    gather_k<2, 1, true><<<GG1, 256, 0, stream>>>(hA, hC, dinv, bg6, ebn, rowptr, d_out, 0.25f, 0, 128);
}